// Round 21
// baseline (183.661 us; speedup 1.0000x reference)
//
#include <hip/hip_runtime.h>

typedef __bf16 bf16_t;
typedef bf16_t bf16x8 __attribute__((ext_vector_type(8)));
typedef bf16_t bf16x4 __attribute__((ext_vector_type(4)));
typedef float  f32x4  __attribute__((ext_vector_type(4)));

#define D2 4096
#define NB 8192   // total batch rows (4*2048)

// ws layout: [0,64MB) mid bf16 | [64MB, +4MB) w1p | [+4MB, +4MB) w2q
#define MID_BYTES  67108864UL
#define W1P_OFF    67108864UL
#define W2P_OFF    71303168UL
#define WS_NEED    75497472UL

typedef const __attribute__((address_space(1))) void* gas_ptr;
typedef __attribute__((address_space(3))) void* las_ptr;

__device__ __forceinline__ void cvt_store16(bf16_t* dst, f32x4 a, f32x4 b) {
    bf16x8 v;
    v[0] = (bf16_t)a[0]; v[1] = (bf16_t)a[1]; v[2] = (bf16_t)a[2]; v[3] = (bf16_t)a[3];
    v[4] = (bf16_t)b[0]; v[5] = (bf16_t)b[1]; v[6] = (bf16_t)b[2]; v[7] = (bf16_t)b[3];
    *reinterpret_cast<bf16x8*>(dst) = v;
}

__device__ __forceinline__ bf16x8 cvt8(f32x4 a, f32x4 b) {
    bf16x8 v;
    v[0] = (bf16_t)a[0]; v[1] = (bf16_t)a[1]; v[2] = (bf16_t)a[2]; v[3] = (bf16_t)a[3];
    v[4] = (bf16_t)b[0]; v[5] = (bf16_t)b[1]; v[6] = (bf16_t)b[2]; v[7] = (bf16_t)b[3];
    return v;
}

// ===== prep 1: w1p[(((kp*16+ks)*8+wv)*4+tf)*64+lane] = w1[kp][wv+8*(tf*16+lo)][ks*32+hi*8 ..+8]
__global__ __launch_bounds__(256)
void prep_w1(const float* __restrict__ w1, bf16x8* __restrict__ w1p)
{
    const int gid  = blockIdx.x * 256 + threadIdx.x;   // 262144 threads
    const int lane = gid & 63;
    const int tf   = (gid >> 6) & 3;
    const int wv   = (gid >> 8) & 7;
    const int ks   = (gid >> 11) & 15;
    const int kp   = gid >> 15;
    const int lo   = lane & 15;
    const int hi   = lane >> 4;
    const int q    = wv + 8 * (tf * 16 + lo);
    const float* src = w1 + ((size_t)kp * 512 + q) * 512 + ks * 32 + hi * 8;
    f32x4 a0 = *reinterpret_cast<const f32x4*>(src);
    f32x4 a1 = *reinterpret_cast<const f32x4*>(src + 4);
    w1p[gid] = cvt8(a0, a1);
}

// ===== prep 2 (v2): w2q wave-FRAGMENT order (B-operand read directly from L2, no LDS)
// w2q[gid] (bf16x8): gid = w*8192 + ks*2048 + s0*256 + sq*64 + lane, w = l*4+rc
//   = bf16(w2[l][s0*64 + sq*16 + lo][rc*128 + ks*32 + hi*8 .. +8]), lane = hi*16+lo
__global__ __launch_bounds__(256)
void prep_w2q(const float* __restrict__ w2, bf16x8* __restrict__ w2q)
{
    const int gid  = blockIdx.x * 256 + threadIdx.x;   // 262144 threads
    const int lane = gid & 63;
    const int sq   = (gid >> 6) & 3;
    const int s0   = (gid >> 8) & 7;
    const int ks   = (gid >> 11) & 3;
    const int w    = gid >> 13;                        // 0..31
    const int l    = w >> 2;
    const int rc   = w & 3;
    const int lo   = lane & 15;
    const int hi   = lane >> 4;
    const float* src = w2 + ((size_t)l * 512 + s0 * 64 + sq * 16 + lo) * 512
                          + rc * 128 + ks * 32 + hi * 8;
    f32x4 a0 = *reinterpret_cast<const f32x4*>(src);
    f32x4 a1 = *reinterpret_cast<const f32x4*>(src + 4);
    w2q[gid] = cvt8(a0, a1);
}

// ================= Kernel 1 (v8): round-6 schedule + launch_bounds(512,3) — r16 verified =====
__global__ __launch_bounds__(512, 3)
void butterfly_k1b(const float* __restrict__ x,
                   const bf16x8* __restrict__ w1p,
                   bf16_t* __restrict__ mid)
{
    __shared__ bf16_t Xs[2][64][72];   // 18,432 B

    const int tid  = threadIdx.x;
    const int lane = tid & 63;
    const int wid  = tid >> 6;      // wave = l
    const int hi   = lane >> 4;
    const int lo   = lane & 15;

    const int kp = blockIdx.x & 7;
    const int b0 = (blockIdx.x >> 3) * 64;

    const int rs = tid >> 3;        // staging row
    const int sg = tid & 7;         // staging 32B segment

    const float* xbase = x + (size_t)(b0 + rs) * D2 + kp * 512 + sg * 8;
    const bf16x8* aw   = w1p + ((size_t)kp * 512 + wid * 4) * 64 + lane;

    f32x4 rx0 = *reinterpret_cast<const f32x4*>(xbase);
    f32x4 rx1 = *reinterpret_cast<const f32x4*>(xbase + 4);

    bf16x8 afr[2][4];
#pragma unroll
    for (int tf = 0; tf < 4; ++tf) afr[0][tf] = aw[(size_t)tf * 64];   // ks = 0

    f32x4 acc[4][4];
#pragma unroll
    for (int tf = 0; tf < 4; ++tf)
#pragma unroll
        for (int mf = 0; mf < 4; ++mf) acc[tf][mf] = {0.f, 0.f, 0.f, 0.f};

#pragma unroll 1
    for (int it = 0; it < 8; ++it) {
        const int buf = it & 1;
        *reinterpret_cast<bf16x8*>(&Xs[buf][rs][sg * 8]) = cvt8(rx0, rx1);
        if (it < 7) {
            rx0 = *reinterpret_cast<const f32x4*>(xbase + (it + 1) * 64);
            rx1 = *reinterpret_cast<const f32x4*>(xbase + (it + 1) * 64 + 4);
        }
        asm volatile("s_waitcnt lgkmcnt(0)" ::: "memory");
        __builtin_amdgcn_s_barrier();
#pragma unroll
        for (int kcs = 0; kcs < 2; ++kcs) {
            const int ks  = it * 2 + kcs;
            const int cur = kcs & 1;
            if (ks + 1 < 16) {
#pragma unroll
                for (int tf = 0; tf < 4; ++tf)
                    afr[cur ^ 1][tf] = aw[(size_t)((ks + 1) * 32 + tf) * 64];
            }
            bf16x8 b[4];
#pragma unroll
            for (int mf = 0; mf < 4; ++mf)
                b[mf] = *reinterpret_cast<const bf16x8*>(&Xs[buf][mf * 16 + lo][kcs * 32 + hi * 8]);
#pragma unroll
            for (int tf = 0; tf < 4; ++tf)
#pragma unroll
                for (int mf = 0; mf < 4; ++mf)
                    acc[tf][mf] = __builtin_amdgcn_mfma_f32_16x16x32_bf16(afr[cur][tf], b[mf], acc[tf][mf], 0, 0, 0);
        }
    }

    // store: D[t][m] -> mid[wid][b0+m][kp*64+t], t = tf*16 + hi*4 + r  (verified layout)
#pragma unroll
    for (int tf = 0; tf < 4; ++tf) {
#pragma unroll
        for (int mf = 0; mf < 4; ++mf) {
            bf16x4 p;
#pragma unroll
            for (int r = 0; r < 4; ++r) p[r] = (bf16_t)acc[tf][mf][r];
            const size_t addr = ((size_t)wid * NB + b0 + mf * 16 + lo) * 512
                              + kp * 64 + tf * 16 + hi * 4;
            *reinterpret_cast<bf16x4*>(mid + addr) = p;
        }
    }
}

// ================= Kernel 2 (v9): wave re-tile (4 mq x 2 sh) — half the A-LDS reads =====
// Each wave owns 16 rows x 32 s-cols: per window 4 af ds_reads feed 2 MFMAs each
// (A-duplication 4x -> 2x; LDS traffic/window 64KB -> 32KB; bank conflicts halve).
// B frags: kh1 single slot (loaded+consumed in-window, WAR-ordered by compiler);
// kh0 single slot (w+1's loaded after w's kh0 MFMAs). Same 32 B-VGPR as v7.1.
// vmcnt: loop=6 {stage(w+2)[2] + k0(w+1)[4]}; w=30 -> 4; prologue full drain.
__global__ __launch_bounds__(512, 2)
void butterfly_k2b(const bf16_t* __restrict__ mid,
                   const char* __restrict__ w2q,
                   const float* __restrict__ bias,
                   float* __restrict__ out)
{
    __shared__ bf16_t Ms[3][64][128];    // 48 KB

    const int tid  = threadIdx.x;
    const int lane = tid & 63;
    const int wid  = tid >> 6;
    const int hi   = lane >> 4;
    const int lo   = lane & 15;

    const int r    = blockIdx.x & 7;          // XCD under round-robin dispatch
    const int g    = blockIdx.x >> 3;         // per-XCD sequence number
    const int s0   = g & 7;                   // s0 cycles fastest within an XCD
    const int tile = (g >> 3) * 8 + r;        // tiles = r (mod 8) pinned to XCD r
    const int b0   = tile * 64;

    const int mq = wid >> 1;   // 0..3 : 16-row block
    const int sh = wid & 1;    // 0..1 : 32-col s half

    // per-wave w2q fragment bases for sf=0,1; stride 2048 bf16x8 per (w*4+ks)
    const bf16x8* bwq0 = reinterpret_cast<const bf16x8*>(w2q)
                       + (size_t)((s0 * 4 + sh * 2 + 0) * 64 + lane);
    const bf16x8* bwq1 = reinterpret_cast<const bf16x8*>(w2q)
                       + (size_t)((s0 * 4 + sh * 2 + 1) * 64 + lane);

    f32x4 acc[8][2];
#pragma unroll
    for (int l = 0; l < 8; ++l)
#pragma unroll
        for (int sf = 0; sf < 2; ++sf) acc[l][sf] = {0.f, 0.f, 0.f, 0.f};

    // stage Ms for window wn into buffer bufx: 2 global_load_lds per wave
    auto stageMs = [&](int wn, int bufx) {
        const int lx  = wn >> 2;
        const int rcx = wn & 3;
#pragma unroll
        for (int i = 0; i < 2; ++i) {
            const int r4  = (wid << 3) + (i << 2);
            const int row = r4 + hi;
            const size_t gbyte = (((size_t)lx * NB + b0 + row) * 512 + rcx * 128) * 2
                               + (size_t)((lo * 16) ^ ((row & 7) << 4));
            __builtin_amdgcn_global_load_lds(
                (gas_ptr)((const char*)mid + gbyte),
                (las_ptr)&Ms[bufx][r4][0], 16, 0, 0);
        }
    };

    bf16x8 k0[2][2];   // [sf][ks in {0,1}] — kh0, single slot (w+1's loaded after w's use)
    bf16x8 k1[2][2];   // [sf][ks in {2,3}] — kh1, loaded & consumed in-window

    // prologue: Ms(0),Ms(1) + k0(window 0); FULL drain (order-robust — r18 lesson)
    stageMs(0, 0);
    stageMs(1, 1);
    k0[0][0] = bwq0[(size_t)0 * 2048]; k0[0][1] = bwq0[(size_t)1 * 2048];
    k0[1][0] = bwq1[(size_t)0 * 2048]; k0[1][1] = bwq1[(size_t)1 * 2048];
    asm volatile("s_waitcnt vmcnt(0)" ::: "memory");
    __builtin_amdgcn_s_barrier();

#pragma unroll
    for (int w = 0; w < 32; ++w) {
        const int l = w >> 2;
        const char* mbase = (const char*)&Ms[w % 3][0][0];
        const int arow = mq * 16 + lo;
        // ---- 1. kh1 loads for THIS window (oldest ops of the window) ----
        k1[0][0] = bwq0[(size_t)(w * 4 + 2) * 2048];
        k1[0][1] = bwq0[(size_t)(w * 4 + 3) * 2048];
        k1[1][0] = bwq1[(size_t)(w * 4 + 2) * 2048];
        k1[1][1] = bwq1[(size_t)(w * 4 + 3) * 2048];
        // ---- 2. stage Ms(w+2) ----
        if (w + 2 < 32) stageMs(w + 2, (w + 2) % 3);
        // ---- 3. compute kh0 (compiler waits for k0 loaded last window) ----
#pragma unroll
        for (int ks = 0; ks < 2; ++ks) {
            const int cb = (ks * 64 + hi * 16) ^ ((arow & 7) << 4);
            bf16x8 af = *reinterpret_cast<const bf16x8*>(mbase + arow * 256 + cb);
            acc[l][0] = __builtin_amdgcn_mfma_f32_16x16x32_bf16(af, k0[0][ks], acc[l][0], 0, 0, 0);
            acc[l][1] = __builtin_amdgcn_mfma_f32_16x16x32_bf16(af, k0[1][ks], acc[l][1], 0, 0, 0);
        }
        // ---- 4. kh0 loads for w+1 (WAR after step 3, enforced by reg deps) ----
        if (w + 1 < 32) {
            k0[0][0] = bwq0[(size_t)((w + 1) * 4 + 0) * 2048];
            k0[0][1] = bwq0[(size_t)((w + 1) * 4 + 1) * 2048];
            k0[1][0] = bwq1[(size_t)((w + 1) * 4 + 0) * 2048];
            k0[1][1] = bwq1[(size_t)((w + 1) * 4 + 1) * 2048];
        }
        // ---- 5. compute kh1 (compiler waits for step-1 loads; stage stays in flight) ----
#pragma unroll
        for (int ks = 2; ks < 4; ++ks) {
            const int cb = (ks * 64 + hi * 16) ^ ((arow & 7) << 4);
            bf16x8 af = *reinterpret_cast<const bf16x8*>(mbase + arow * 256 + cb);
            acc[l][0] = __builtin_amdgcn_mfma_f32_16x16x32_bf16(af, k1[0][ks - 2], acc[l][0], 0, 0, 0);
            acc[l][1] = __builtin_amdgcn_mfma_f32_16x16x32_bf16(af, k1[1][ks - 2], acc[l][1], 0, 0, 0);
        }
        // ---- 6. barrier: stage(w+1) retired; allowed {stage(w+2), k0(w+1)} ----
        if (w < 30) {
            asm volatile("s_waitcnt vmcnt(6)" ::: "memory");
            __builtin_amdgcn_s_barrier();
        } else if (w == 30) {
            asm volatile("s_waitcnt vmcnt(4)" ::: "memory");   // no stage(32); k0(31) flying
            __builtin_amdgcn_s_barrier();
        }
    }

    // epilogue: per sf, lane owns s = s0*64 + (sh*2+sf)*16 + lo; cols 8s..8s+7 = acc[l]
#pragma unroll
    for (int sf = 0; sf < 2; ++sf) {
        const int scol = s0 * 64 + (sh * 2 + sf) * 16 + lo;
        const float* bp = bias + (size_t)scol * 8;
        f32x4 bv0 = *reinterpret_cast<const f32x4*>(bp);
        f32x4 bv1 = *reinterpret_cast<const f32x4*>(bp + 4);
#pragma unroll
        for (int rr = 0; rr < 4; ++rr) {
            const int m = mq * 16 + hi * 4 + rr;
            f32x4 v0, v1;
#pragma unroll
            for (int l = 0; l < 4; ++l) {
                v0[l] = acc[l][sf][rr]     + bv0[l];
                v1[l] = acc[l + 4][sf][rr] + bv1[l];
            }
            float* op = out + (size_t)(b0 + m) * D2 + (size_t)scol * 8;
            *reinterpret_cast<f32x4*>(op)     = v0;
            *reinterpret_cast<f32x4*>(op + 4) = v1;
        }
    }
}

// ================= middle fallback (ws >= 67MB): round-3 kernels =================
__global__ __launch_bounds__(512, 4)
void butterfly_k1(const float* __restrict__ x,
                  const float* __restrict__ w1,
                  bf16_t* __restrict__ mid)
{
    __shared__ bf16_t Xs[64][40];
    __shared__ bf16_t W1s[512][40];

    const int tid  = threadIdx.x;
    const int lane = tid & 63;
    const int wid  = tid >> 6;
    const int hi   = lane >> 4;
    const int lo   = lane & 15;

    const int kp = blockIdx.x & 7;
    const int b0 = (blockIdx.x >> 3) * 64;

    const int rs = tid >> 3;
    const int sg = tid & 7;

    const float* xbase  = x  + (size_t)(b0 + rs) * D2 + kp * 512 + sg * 4;
    const float* w1base = w1 + (size_t)kp * 512 * 512 + sg * 4;

    f32x4 rx, rw[8];
    rx = *reinterpret_cast<const f32x4*>(xbase);
#pragma unroll
    for (int g = 0; g < 8; ++g)
        rw[g] = *reinterpret_cast<const f32x4*>(w1base + (size_t)(g + 8 * rs) * 512);

    f32x4 acc[4][4];
#pragma unroll
    for (int tf = 0; tf < 4; ++tf)
#pragma unroll
        for (int mf = 0; mf < 4; ++mf) acc[tf][mf] = {0.f, 0.f, 0.f, 0.f};

#pragma unroll 1
    for (int kc = 0; kc < 16; ++kc) {
        {
            bf16x4 t;
#pragma unroll
            for (int i = 0; i < 4; ++i) t[i] = (bf16_t)rx[i];
            *reinterpret_cast<bf16x4*>(&Xs[rs][sg * 4]) = t;
        }
#pragma unroll
        for (int g = 0; g < 8; ++g) {
            bf16x4 t;
#pragma unroll
            for (int i = 0; i < 4; ++i) t[i] = (bf16_t)rw[g][i];
            *reinterpret_cast<bf16x4*>(&W1s[g * 64 + rs][sg * 4]) = t;
        }
        __syncthreads();

        if (kc < 15) {
            const int off = (kc + 1) * 32;
            rx = *reinterpret_cast<const f32x4*>(xbase + off);
#pragma unroll
            for (int g = 0; g < 8; ++g)
                rw[g] = *reinterpret_cast<const f32x4*>(w1base + (size_t)(g + 8 * rs) * 512 + off);
        }

        bf16x8 a[4], b[4];
#pragma unroll
        for (int tf = 0; tf < 4; ++tf)
            a[tf] = *reinterpret_cast<const bf16x8*>(&W1s[wid * 64 + tf * 16 + lo][hi * 8]);
#pragma unroll
        for (int mf = 0; mf < 4; ++mf)
            b[mf] = *reinterpret_cast<const bf16x8*>(&Xs[mf * 16 + lo][hi * 8]);
#pragma unroll
        for (int tf = 0; tf < 4; ++tf)
#pragma unroll
            for (int mf = 0; mf < 4; ++mf)
                acc[tf][mf] = __builtin_amdgcn_mfma_f32_16x16x32_bf16(a[tf], b[mf], acc[tf][mf], 0, 0, 0);
        __syncthreads();
    }

#pragma unroll
    for (int tf = 0; tf < 4; ++tf) {
#pragma unroll
        for (int mf = 0; mf < 4; ++mf) {
            bf16x4 p;
#pragma unroll
            for (int r = 0; r < 4; ++r) p[r] = (bf16_t)acc[tf][mf][r];
            const size_t addr = ((size_t)wid * NB + b0 + mf * 16 + lo) * 512
                              + kp * 64 + tf * 16 + hi * 4;
            *reinterpret_cast<bf16x4*>(mid + addr) = p;
        }
    }
}

__global__ __launch_bounds__(512, 4)
void butterfly_k2(const bf16_t* __restrict__ mid,
                  const float* __restrict__ w2,
                  const float* __restrict__ bias,
                  float* __restrict__ out)
{
    __shared__ bf16_t Ms[64][128];
    __shared__ bf16_t W2s[64][136];

    const int tid  = threadIdx.x;
    const int lane = tid & 63;
    const int wid  = tid >> 6;
    const int hi   = lane >> 4;
    const int lo   = lane & 15;

    const int s0 = blockIdx.x & 7;
    const int b0 = (blockIdx.x >> 3) * 64;

    const int mhalf = wid >> 2;
    const int sq    = wid & 3;

    const int srow = tid >> 3;
    const int sseg = tid & 7;

    f32x4 acc[8][2];
#pragma unroll
    for (int l = 0; l < 8; ++l)
#pragma unroll
        for (int mf = 0; mf < 2; ++mf) acc[l][mf] = {0.f, 0.f, 0.f, 0.f};

#pragma unroll
    for (int l = 0; l < 8; ++l) {
#pragma unroll 1
        for (int rc = 0; rc < 4; ++rc) {
#pragma unroll
            for (int i = 0; i < 2; ++i) {
                const int r4  = (wid << 3) + (i << 2);
                const int row = r4 + hi;
                const size_t gbyte = (((size_t)l * NB + b0 + row) * 512 + rc * 128) * 2
                                   + (size_t)((lo * 16) ^ ((row & 7) << 4));
                __builtin_amdgcn_global_load_lds(
                    (gas_ptr)((const char*)mid + gbyte),
                    (las_ptr)&Ms[r4][0], 16, 0, 0);
            }
            {
                const float* wp = w2 + ((size_t)l * 512 + s0 * 64 + srow) * 512 + rc * 128 + sseg * 16;
                f32x4 a0 = *reinterpret_cast<const f32x4*>(wp);
                f32x4 a1 = *reinterpret_cast<const f32x4*>(wp + 4);
                f32x4 a2 = *reinterpret_cast<const f32x4*>(wp + 8);
                f32x4 a3 = *reinterpret_cast<const f32x4*>(wp + 12);
                cvt_store16(&W2s[srow][sseg * 16],     a0, a1);
                cvt_store16(&W2s[srow][sseg * 16 + 8], a2, a3);
            }
            __syncthreads();
#pragma unroll
            for (int ks = 0; ks < 4; ++ks) {
                bf16x8 bf = *reinterpret_cast<const bf16x8*>(&W2s[sq * 16 + lo][ks * 32 + hi * 8]);
#pragma unroll
                for (int mf = 0; mf < 2; ++mf) {
                    const int arow = mhalf * 32 + mf * 16 + lo;
                    const int cb   = (ks * 64 + hi * 16) ^ ((arow & 7) << 4);
                    bf16x8 af = *reinterpret_cast<const bf16x8*>(
                        (const char*)&Ms[0][0] + arow * 256 + cb);
                    acc[l][mf] = __builtin_amdgcn_mfma_f32_16x16x32_bf16(af, bf, acc[l][mf], 0, 0, 0);
                }
            }
            __syncthreads();
        }
    }

    const int scol = s0 * 64 + sq * 16 + lo;
    const float* bp = bias + (size_t)scol * 8;
    f32x4 bv0 = *reinterpret_cast<const f32x4*>(bp);
    f32x4 bv1 = *reinterpret_cast<const f32x4*>(bp + 4);
#pragma unroll
    for (int mf = 0; mf < 2; ++mf) {
#pragma unroll
        for (int r = 0; r < 4; ++r) {
            const int m = mhalf * 32 + mf * 16 + hi * 4 + r;
            f32x4 v0, v1;
#pragma unroll
            for (int l = 0; l < 4; ++l) {
                v0[l] = acc[l][mf][r]     + bv0[l];
                v1[l] = acc[l + 4][mf][r] + bv1[l];
            }
            float* op = out + (size_t)(b0 + m) * D2 + (size_t)scol * 8;
            *reinterpret_cast<f32x4*>(op)     = v0;
            *reinterpret_cast<f32x4*>(op + 4) = v1;
        }
    }
}

// ================= bottom fallback: round-1 fused kernel =================
__global__ __launch_bounds__(512, 1)
void butterfly_fused(const float* __restrict__ x,
                     const float* __restrict__ w1,
                     const float* __restrict__ w2,
                     const float* __restrict__ bias,
                     float* __restrict__ out)
{
    __shared__ bf16_t mid[64][520];
    __shared__ union {
        struct { bf16_t Xs[64][136]; bf16_t W1s[64][136]; } p1;
        bf16_t W2s[512][72];
    } u;
    __shared__ float bias_l[512];

    const int tid  = threadIdx.x;
    const int lane = tid & 63;
    const int wid  = tid >> 6;
    const int hi   = lane >> 4;
    const int lo   = lane & 15;

    const int bid  = blockIdx.x;
    const int l    = bid & 7;
    const int tile = bid >> 3;
    const int b0   = tile * 64;

    bias_l[tid] = bias[(tid << 3) + l];

    const int srow = tid >> 3;
    const int sseg = tid & 7;
    const int ttile = wid >> 1;
    const int mhalf = wid & 1;

    for (int kp = 0; kp < 8; ++kp) {
        f32x4 acc0 = {0.f, 0.f, 0.f, 0.f};
        f32x4 acc1 = {0.f, 0.f, 0.f, 0.f};
        for (int kc = 0; kc < 4; ++kc) {
            {
                const float* xp = x + (size_t)(b0 + srow) * D2 + kp * 512 + kc * 128 + sseg * 16;
                f32x4 a0 = *reinterpret_cast<const f32x4*>(xp);
                f32x4 a1 = *reinterpret_cast<const f32x4*>(xp + 4);
                f32x4 a2 = *reinterpret_cast<const f32x4*>(xp + 8);
                f32x4 a3 = *reinterpret_cast<const f32x4*>(xp + 12);
                cvt_store16(&u.p1.Xs[srow][sseg * 16],     a0, a1);
                cvt_store16(&u.p1.Xs[srow][sseg * 16 + 8], a2, a3);
            }
            {
                const float* wp = w1 + ((size_t)kp * 512 + (l + 8 * srow)) * 512 + kc * 128 + sseg * 16;
                f32x4 a0 = *reinterpret_cast<const f32x4*>(wp);
                f32x4 a1 = *reinterpret_cast<const f32x4*>(wp + 4);
                f32x4 a2 = *reinterpret_cast<const f32x4*>(wp + 8);
                f32x4 a3 = *reinterpret_cast<const f32x4*>(wp + 12);
                cvt_store16(&u.p1.W1s[srow][sseg * 16],     a0, a1);
                cvt_store16(&u.p1.W1s[srow][sseg * 16 + 8], a2, a3);
            }
            __syncthreads();
#pragma unroll
            for (int ks = 0; ks < 4; ++ks) {
                bf16x8 af  = *reinterpret_cast<const bf16x8*>(&u.p1.W1s[ttile * 16 + lo][ks * 32 + hi * 8]);
                bf16x8 bf0 = *reinterpret_cast<const bf16x8*>(&u.p1.Xs[mhalf * 32 + lo][ks * 32 + hi * 8]);
                bf16x8 bf1 = *reinterpret_cast<const bf16x8*>(&u.p1.Xs[mhalf * 32 + 16 + lo][ks * 32 + hi * 8]);
                acc0 = __builtin_amdgcn_mfma_f32_16x16x32_bf16(af, bf0, acc0, 0, 0, 0);
                acc1 = __builtin_amdgcn_mfma_f32_16x16x32_bf16(af, bf1, acc1, 0, 0, 0);
            }
            __syncthreads();
        }
        {
            const int rb = kp * 64 + ttile * 16 + hi * 4;
            bf16x4 p0, p1;
#pragma unroll
            for (int r = 0; r < 4; ++r) { p0[r] = (bf16_t)acc0[r]; p1[r] = (bf16_t)acc1[r]; }
            *reinterpret_cast<bf16x4*>(&mid[mhalf * 32 + lo][rb])      = p0;
            *reinterpret_cast<bf16x4*>(&mid[mhalf * 32 + 16 + lo][rb]) = p1;
        }
    }
    __syncthreads();

    const int mtile = wid >> 1;
    const int shalf = wid & 1;

    f32x4 acc[16];
#pragma unroll
    for (int j = 0; j < 16; ++j) acc[j] = {0.f, 0.f, 0.f, 0.f};

    for (int rc = 0; rc < 8; ++rc) {
#pragma unroll
        for (int ss = 0; ss < 8; ++ss) {
            const int s = (tid >> 3) + (ss << 6);
            const float* wp = w2 + ((size_t)l * 512 + s) * 512 + rc * 64 + sseg * 8;
            f32x4 a0 = *reinterpret_cast<const f32x4*>(wp);
            f32x4 a1 = *reinterpret_cast<const f32x4*>(wp + 4);
            cvt_store16(&u.W2s[s][sseg * 8], a0, a1);
        }
        __syncthreads();
#pragma unroll
        for (int ks = 0; ks < 2; ++ks) {
            bf16x8 af = *reinterpret_cast<const bf16x8*>(&mid[mtile * 16 + lo][rc * 64 + ks * 32 + hi * 8]);
#pragma unroll
            for (int j = 0; j < 16; ++j) {
                bf16x8 bfj = *reinterpret_cast<const bf16x8*>(&u.W2s[shalf * 256 + j * 16 + lo][ks * 32 + hi * 8]);
                acc[j] = __builtin_amdgcn_mfma_f32_16x16x32_bf16(af, bfj, acc[j], 0, 0, 0);
            }
        }
        __syncthreads();
    }

#pragma unroll
    for (int j = 0; j < 16; ++j) {
        const int s = shalf * 256 + j * 16 + lo;
        const float bv = bias_l[s];
        const size_t col = ((size_t)s << 3) + l;
#pragma unroll
        for (int r = 0; r < 4; ++r) {
            const int m = mtile * 16 + hi * 4 + r;
            out[(size_t)(b0 + m) * D2 + col] = acc[j][r] + bv;
        }
    }
}

extern "C" void kernel_launch(void* const* d_in, const int* in_sizes, int n_in,
                              void* d_out, int out_size, void* d_ws, size_t ws_size,
                              hipStream_t stream) {
    const float* x    = (const float*)d_in[0];
    const float* w1   = (const float*)d_in[1];
    const float* w2   = (const float*)d_in[2];
    const float* bias = (const float*)d_in[3];
    float* out = (float*)d_out;

    if (ws_size >= WS_NEED) {
        bf16_t* mid = (bf16_t*)d_ws;
        bf16x8* w1p = (bf16x8*)((char*)d_ws + W1P_OFF);
        bf16x8* w2q = (bf16x8*)((char*)d_ws + W2P_OFF);
        hipLaunchKernelGGL(prep_w1,  dim3(1024), dim3(256), 0, stream, w1, w1p);
        hipLaunchKernelGGL(prep_w2q, dim3(1024), dim3(256), 0, stream, w2, w2q);
        hipLaunchKernelGGL(butterfly_k1b, dim3(1024), dim3(512), 0, stream, x, w1p, mid);
        hipLaunchKernelGGL(butterfly_k2b, dim3(1024), dim3(512), 0, stream,
                           mid, (const char*)w2q, bias, out);
    } else if (ws_size >= MID_BYTES) {
        bf16_t* mid = (bf16_t*)d_ws;
        hipLaunchKernelGGL(butterfly_k1, dim3(1024), dim3(512), 0, stream, x, w1, mid);
        hipLaunchKernelGGL(butterfly_k2, dim3(1024), dim3(512), 0, stream, mid, w2, bias, out);
    } else {
        hipLaunchKernelGGL(butterfly_fused, dim3(1024), dim3(512), 0, stream, x, w1, w2, bias, out);
    }
}

// Round 22
// 158.363 us; speedup vs baseline: 1.1597x; 1.1597x over previous
//
#include <hip/hip_runtime.h>

typedef __bf16 bf16_t;
typedef bf16_t bf16x8 __attribute__((ext_vector_type(8)));
typedef bf16_t bf16x4 __attribute__((ext_vector_type(4)));
typedef float  f32x4  __attribute__((ext_vector_type(4)));

#define D2 4096
#define NB 8192   // total batch rows (4*2048)

// ws layout: [0,64MB) mid bf16 | [64MB, +4MB) w1p | [+4MB, +4MB) w2p
#define MID_BYTES  67108864UL
#define W1P_OFF    67108864UL
#define W2P_OFF    71303168UL
#define WS_NEED    75497472UL

typedef const __attribute__((address_space(1))) void* gas_ptr;
typedef __attribute__((address_space(3))) void* las_ptr;

__device__ __forceinline__ void cvt_store16(bf16_t* dst, f32x4 a, f32x4 b) {
    bf16x8 v;
    v[0] = (bf16_t)a[0]; v[1] = (bf16_t)a[1]; v[2] = (bf16_t)a[2]; v[3] = (bf16_t)a[3];
    v[4] = (bf16_t)b[0]; v[5] = (bf16_t)b[1]; v[6] = (bf16_t)b[2]; v[7] = (bf16_t)b[3];
    *reinterpret_cast<bf16x8*>(dst) = v;
}

__device__ __forceinline__ bf16x8 cvt8(f32x4 a, f32x4 b) {
    bf16x8 v;
    v[0] = (bf16_t)a[0]; v[1] = (bf16_t)a[1]; v[2] = (bf16_t)a[2]; v[3] = (bf16_t)a[3];
    v[4] = (bf16_t)b[0]; v[5] = (bf16_t)b[1]; v[6] = (bf16_t)b[2]; v[7] = (bf16_t)b[3];
    return v;
}

// ===== prep 1: w1p[(((kp*16+ks)*8+wv)*4+tf)*64+lane] = w1[kp][wv+8*(tf*16+lo)][ks*32+hi*8 ..+8]
__global__ __launch_bounds__(256)
void prep_w1(const float* __restrict__ w1, bf16x8* __restrict__ w1p)
{
    const int gid  = blockIdx.x * 256 + threadIdx.x;   // 262144 threads
    const int lane = gid & 63;
    const int tf   = (gid >> 6) & 3;
    const int wv   = (gid >> 8) & 7;
    const int ks   = (gid >> 11) & 15;
    const int kp   = gid >> 15;
    const int lo   = lane & 15;
    const int hi   = lane >> 4;
    const int q    = wv + 8 * (tf * 16 + lo);
    const float* src = w1 + ((size_t)kp * 512 + q) * 512 + ks * 32 + hi * 8;
    f32x4 a0 = *reinterpret_cast<const f32x4*>(src);
    f32x4 a1 = *reinterpret_cast<const f32x4*>(src + 4);
    w1p[gid] = cvt8(a0, a1);
}

// ===== prep 2: w2p LDS-image, chunk (l,s0,rc) 16KB, row-XOR swizzle baked in
__global__ __launch_bounds__(256)
void prep_w2(const float* __restrict__ w2, bf16x8* __restrict__ w2p)
{
    const int gid   = blockIdx.x * 256 + threadIdx.x;  // 262144 threads
    const int cslot = gid & 15;
    const int row   = (gid >> 4) & 63;
    const int rc    = (gid >> 10) & 3;
    const int s0    = (gid >> 12) & 7;
    const int l     = gid >> 15;
    const int c0    = ((cslot * 16) ^ ((row & 7) << 4)) >> 1;
    const float* src = w2 + ((size_t)l * 512 + s0 * 64 + row) * 512 + rc * 128 + c0;
    f32x4 a0 = *reinterpret_cast<const f32x4*>(src);
    f32x4 a1 = *reinterpret_cast<const f32x4*>(src + 4);
    w2p[gid] = cvt8(a0, a1);
}

// ================= Kernel 1 (v8): round-6 schedule + launch_bounds(512,3) — r16 verified =====
__global__ __launch_bounds__(512, 3)
void butterfly_k1b(const float* __restrict__ x,
                   const bf16x8* __restrict__ w1p,
                   bf16_t* __restrict__ mid)
{
    __shared__ bf16_t Xs[2][64][72];   // 18,432 B

    const int tid  = threadIdx.x;
    const int lane = tid & 63;
    const int wid  = tid >> 6;      // wave = l
    const int hi   = lane >> 4;
    const int lo   = lane & 15;

    const int kp = blockIdx.x & 7;
    const int b0 = (blockIdx.x >> 3) * 64;

    const int rs = tid >> 3;        // staging row
    const int sg = tid & 7;         // staging 32B segment

    const float* xbase = x + (size_t)(b0 + rs) * D2 + kp * 512 + sg * 8;
    const bf16x8* aw   = w1p + ((size_t)kp * 512 + wid * 4) * 64 + lane;

    f32x4 rx0 = *reinterpret_cast<const f32x4*>(xbase);
    f32x4 rx1 = *reinterpret_cast<const f32x4*>(xbase + 4);

    bf16x8 afr[2][4];
#pragma unroll
    for (int tf = 0; tf < 4; ++tf) afr[0][tf] = aw[(size_t)tf * 64];   // ks = 0

    f32x4 acc[4][4];
#pragma unroll
    for (int tf = 0; tf < 4; ++tf)
#pragma unroll
        for (int mf = 0; mf < 4; ++mf) acc[tf][mf] = {0.f, 0.f, 0.f, 0.f};

#pragma unroll 1
    for (int it = 0; it < 8; ++it) {
        const int buf = it & 1;
        *reinterpret_cast<bf16x8*>(&Xs[buf][rs][sg * 8]) = cvt8(rx0, rx1);
        if (it < 7) {
            rx0 = *reinterpret_cast<const f32x4*>(xbase + (it + 1) * 64);
            rx1 = *reinterpret_cast<const f32x4*>(xbase + (it + 1) * 64 + 4);
        }
        asm volatile("s_waitcnt lgkmcnt(0)" ::: "memory");
        __builtin_amdgcn_s_barrier();
#pragma unroll
        for (int kcs = 0; kcs < 2; ++kcs) {
            const int ks  = it * 2 + kcs;
            const int cur = kcs & 1;
            if (ks + 1 < 16) {
#pragma unroll
                for (int tf = 0; tf < 4; ++tf)
                    afr[cur ^ 1][tf] = aw[(size_t)((ks + 1) * 32 + tf) * 64];
            }
            bf16x8 b[4];
#pragma unroll
            for (int mf = 0; mf < 4; ++mf)
                b[mf] = *reinterpret_cast<const bf16x8*>(&Xs[buf][mf * 16 + lo][kcs * 32 + hi * 8]);
#pragma unroll
            for (int tf = 0; tf < 4; ++tf)
#pragma unroll
                for (int mf = 0; mf < 4; ++mf)
                    acc[tf][mf] = __builtin_amdgcn_mfma_f32_16x16x32_bf16(afr[cur][tf], b[mf], acc[tf][mf], 0, 0, 0);
        }
    }

    // store: D[t][m] -> mid[wid][b0+m][kp*64+t], t = tf*16 + hi*4 + r  (verified layout)
#pragma unroll
    for (int tf = 0; tf < 4; ++tf) {
#pragma unroll
        for (int mf = 0; mf < 4; ++mf) {
            bf16x4 p;
#pragma unroll
            for (int r = 0; r < 4; ++r) p[r] = (bf16_t)acc[tf][mf][r];
            const size_t addr = ((size_t)wid * NB + b0 + mf * 16 + lo) * 512
                              + kp * 64 + tf * 16 + hi * 4;
            *reinterpret_cast<bf16x4*>(mid + addr) = p;
        }
    }
}

// ================= Kernel 2 (v5): counted-vmcnt pipeline + XCD-local mid reuse — r16 best =====
__global__ __launch_bounds__(512, 4)
void butterfly_k2b(const bf16_t* __restrict__ mid,
                   const char* __restrict__ w2p,
                   const float* __restrict__ bias,
                   float* __restrict__ out)
{
    __shared__ bf16_t Ms[2][64][128];    // 32 KB
    __shared__ bf16_t W2s[2][64][128];   // 32 KB

    const int tid  = threadIdx.x;
    const int lane = tid & 63;
    const int wid  = tid >> 6;
    const int hi   = lane >> 4;
    const int lo   = lane & 15;

    const int r    = blockIdx.x & 7;          // XCD under round-robin dispatch
    const int g    = blockIdx.x >> 3;         // per-XCD sequence number
    const int s0   = g & 7;                   // s0 cycles fastest within an XCD
    const int tile = (g >> 3) * 8 + r;        // tiles = r (mod 8) pinned to XCD r
    const int b0   = tile * 64;

    const int mhalf = wid >> 2;
    const int sq    = wid & 3;

    f32x4 acc[8][2];
#pragma unroll
    for (int l = 0; l < 8; ++l)
#pragma unroll
        for (int mf = 0; mf < 2; ++mf) acc[l][mf] = {0.f, 0.f, 0.f, 0.f};

    // stage window wn = (lx*4+rcx) into buffer bufx: 4 global_load_lds per wave
    auto stage = [&](int wn, int bufx) {
        const int lx  = wn >> 2;
        const int rcx = wn & 3;
#pragma unroll
        for (int i = 0; i < 2; ++i) {
            const int r4  = (wid << 3) + (i << 2);
            const int row = r4 + hi;
            const size_t gbyte = (((size_t)lx * NB + b0 + row) * 512 + rcx * 128) * 2
                               + (size_t)((lo * 16) ^ ((row & 7) << 4));
            __builtin_amdgcn_global_load_lds(
                (gas_ptr)((const char*)mid + gbyte),
                (las_ptr)&Ms[bufx][r4][0], 16, 0, 0);
        }
        const size_t chunk = (size_t)(((lx * 8) + s0) * 4 + rcx) * 16384;
#pragma unroll
        for (int i = 0; i < 2; ++i) {
            const int r4 = (wid << 3) + (i << 2);
            __builtin_amdgcn_global_load_lds(
                (gas_ptr)(w2p + chunk + r4 * 256 + lane * 16),
                (las_ptr)&W2s[bufx][r4][0], 16, 0, 0);
        }
    };

    // prologue: 2 windows in flight, retire window 0, keep window 1 flying
    stage(0, 0);
    stage(1, 1);
    asm volatile("s_waitcnt vmcnt(4)" ::: "memory");
    __builtin_amdgcn_s_barrier();

#pragma unroll
    for (int l = 0; l < 8; ++l) {
#pragma unroll
        for (int rc = 0; rc < 4; ++rc) {
            const int w   = l * 4 + rc;
            const int buf = w & 1;
            // ---- compute(w) ----
#pragma unroll
            for (int ks = 0; ks < 4; ++ks) {
                const int srw = sq * 16 + lo;
                const int cbW = (ks * 64 + hi * 16) ^ ((srw & 7) << 4);
                bf16x8 bfr = *reinterpret_cast<const bf16x8*>(
                    (const char*)&W2s[buf][0][0] + srw * 256 + cbW);
#pragma unroll
                for (int mf = 0; mf < 2; ++mf) {
                    const int arow = mhalf * 32 + mf * 16 + lo;
                    const int cb   = (ks * 64 + hi * 16) ^ ((arow & 7) << 4);
                    bf16x8 af = *reinterpret_cast<const bf16x8*>(
                        (const char*)&Ms[buf][0][0] + arow * 256 + cb);
                    acc[l][mf] = __builtin_amdgcn_mfma_f32_16x16x32_bf16(af, bfr, acc[l][mf], 0, 0, 0);
                }
            }
            // ---- sync + stage(w+2), counted vmcnt (never drain mid-loop) ----
            if (w < 31) {
                asm volatile("" ::: "memory");
                __builtin_amdgcn_s_barrier();            // A: all readers of buf done
                if (w + 2 < 32) {
                    stage(w + 2, buf);
                    asm volatile("s_waitcnt vmcnt(4)" ::: "memory");  // stage(w+1) retired
                } else {
                    asm volatile("s_waitcnt vmcnt(0)" ::: "memory");  // epilogue drain
                }
                __builtin_amdgcn_s_barrier();            // B: buf((w+1)&1) ready
            }
        }
    }

    // epilogue: lane owns s = s0*64+sq*16+lo; cols 8s..8s+7 = acc[l=0..7]
    const int scol = s0 * 64 + sq * 16 + lo;
    const float* bp = bias + (size_t)scol * 8;
    f32x4 bv0 = *reinterpret_cast<const f32x4*>(bp);
    f32x4 bv1 = *reinterpret_cast<const f32x4*>(bp + 4);
#pragma unroll
    for (int mf = 0; mf < 2; ++mf) {
#pragma unroll
        for (int rr = 0; rr < 4; ++rr) {
            const int m = mhalf * 32 + mf * 16 + hi * 4 + rr;
            f32x4 v0, v1;
#pragma unroll
            for (int l = 0; l < 4; ++l) {
                v0[l] = acc[l][mf][rr]     + bv0[l];
                v1[l] = acc[l + 4][mf][rr] + bv1[l];
            }
            float* op = out + (size_t)(b0 + m) * D2 + (size_t)scol * 8;
            *reinterpret_cast<f32x4*>(op)     = v0;
            *reinterpret_cast<f32x4*>(op + 4) = v1;
        }
    }
}

// ================= middle fallback (ws >= 67MB): round-3 kernels =================
__global__ __launch_bounds__(512, 4)
void butterfly_k1(const float* __restrict__ x,
                  const float* __restrict__ w1,
                  bf16_t* __restrict__ mid)
{
    __shared__ bf16_t Xs[64][40];
    __shared__ bf16_t W1s[512][40];

    const int tid  = threadIdx.x;
    const int lane = tid & 63;
    const int wid  = tid >> 6;
    const int hi   = lane >> 4;
    const int lo   = lane & 15;

    const int kp = blockIdx.x & 7;
    const int b0 = (blockIdx.x >> 3) * 64;

    const int rs = tid >> 3;
    const int sg = tid & 7;

    const float* xbase  = x  + (size_t)(b0 + rs) * D2 + kp * 512 + sg * 4;
    const float* w1base = w1 + (size_t)kp * 512 * 512 + sg * 4;

    f32x4 rx, rw[8];
    rx = *reinterpret_cast<const f32x4*>(xbase);
#pragma unroll
    for (int g = 0; g < 8; ++g)
        rw[g] = *reinterpret_cast<const f32x4*>(w1base + (size_t)(g + 8 * rs) * 512);

    f32x4 acc[4][4];
#pragma unroll
    for (int tf = 0; tf < 4; ++tf)
#pragma unroll
        for (int mf = 0; mf < 4; ++mf) acc[tf][mf] = {0.f, 0.f, 0.f, 0.f};

#pragma unroll 1
    for (int kc = 0; kc < 16; ++kc) {
        {
            bf16x4 t;
#pragma unroll
            for (int i = 0; i < 4; ++i) t[i] = (bf16_t)rx[i];
            *reinterpret_cast<bf16x4*>(&Xs[rs][sg * 4]) = t;
        }
#pragma unroll
        for (int g = 0; g < 8; ++g) {
            bf16x4 t;
#pragma unroll
            for (int i = 0; i < 4; ++i) t[i] = (bf16_t)rw[g][i];
            *reinterpret_cast<bf16x4*>(&W1s[g * 64 + rs][sg * 4]) = t;
        }
        __syncthreads();

        if (kc < 15) {
            const int off = (kc + 1) * 32;
            rx = *reinterpret_cast<const f32x4*>(xbase + off);
#pragma unroll
            for (int g = 0; g < 8; ++g)
                rw[g] = *reinterpret_cast<const f32x4*>(w1base + (size_t)(g + 8 * rs) * 512 + off);
        }

        bf16x8 a[4], b[4];
#pragma unroll
        for (int tf = 0; tf < 4; ++tf)
            a[tf] = *reinterpret_cast<const bf16x8*>(&W1s[wid * 64 + tf * 16 + lo][hi * 8]);
#pragma unroll
        for (int mf = 0; mf < 4; ++mf)
            b[mf] = *reinterpret_cast<const bf16x8*>(&Xs[mf * 16 + lo][hi * 8]);
#pragma unroll
        for (int tf = 0; tf < 4; ++tf)
#pragma unroll
            for (int mf = 0; mf < 4; ++mf)
                acc[tf][mf] = __builtin_amdgcn_mfma_f32_16x16x32_bf16(a[tf], b[mf], acc[tf][mf], 0, 0, 0);
        __syncthreads();
    }

#pragma unroll
    for (int tf = 0; tf < 4; ++tf) {
#pragma unroll
        for (int mf = 0; mf < 4; ++mf) {
            bf16x4 p;
#pragma unroll
            for (int r = 0; r < 4; ++r) p[r] = (bf16_t)acc[tf][mf][r];
            const size_t addr = ((size_t)wid * NB + b0 + mf * 16 + lo) * 512
                              + kp * 64 + tf * 16 + hi * 4;
            *reinterpret_cast<bf16x4*>(mid + addr) = p;
        }
    }
}

__global__ __launch_bounds__(512, 4)
void butterfly_k2(const bf16_t* __restrict__ mid,
                  const float* __restrict__ w2,
                  const float* __restrict__ bias,
                  float* __restrict__ out)
{
    __shared__ bf16_t Ms[64][128];
    __shared__ bf16_t W2s[64][136];

    const int tid  = threadIdx.x;
    const int lane = tid & 63;
    const int wid  = tid >> 6;
    const int hi   = lane >> 4;
    const int lo   = lane & 15;

    const int s0 = blockIdx.x & 7;
    const int b0 = (blockIdx.x >> 3) * 64;

    const int mhalf = wid >> 2;
    const int sq    = wid & 3;

    const int srow = tid >> 3;
    const int sseg = tid & 7;

    f32x4 acc[8][2];
#pragma unroll
    for (int l = 0; l < 8; ++l)
#pragma unroll
        for (int mf = 0; mf < 2; ++mf) acc[l][mf] = {0.f, 0.f, 0.f, 0.f};

#pragma unroll
    for (int l = 0; l < 8; ++l) {
#pragma unroll 1
        for (int rc = 0; rc < 4; ++rc) {
#pragma unroll
            for (int i = 0; i < 2; ++i) {
                const int r4  = (wid << 3) + (i << 2);
                const int row = r4 + hi;
                const size_t gbyte = (((size_t)l * NB + b0 + row) * 512 + rc * 128) * 2
                                   + (size_t)((lo * 16) ^ ((row & 7) << 4));
                __builtin_amdgcn_global_load_lds(
                    (gas_ptr)((const char*)mid + gbyte),
                    (las_ptr)&Ms[r4][0], 16, 0, 0);
            }
            {
                const float* wp = w2 + ((size_t)l * 512 + s0 * 64 + srow) * 512 + rc * 128 + sseg * 16;
                f32x4 a0 = *reinterpret_cast<const f32x4*>(wp);
                f32x4 a1 = *reinterpret_cast<const f32x4*>(wp + 4);
                f32x4 a2 = *reinterpret_cast<const f32x4*>(wp + 8);
                f32x4 a3 = *reinterpret_cast<const f32x4*>(wp + 12);
                cvt_store16(&W2s[srow][sseg * 16],     a0, a1);
                cvt_store16(&W2s[srow][sseg * 16 + 8], a2, a3);
            }
            __syncthreads();
#pragma unroll
            for (int ks = 0; ks < 4; ++ks) {
                bf16x8 bf = *reinterpret_cast<const bf16x8*>(&W2s[sq * 16 + lo][ks * 32 + hi * 8]);
#pragma unroll
                for (int mf = 0; mf < 2; ++mf) {
                    const int arow = mhalf * 32 + mf * 16 + lo;
                    const int cb   = (ks * 64 + hi * 16) ^ ((arow & 7) << 4);
                    bf16x8 af = *reinterpret_cast<const bf16x8*>(
                        (const char*)&Ms[0][0] + arow * 256 + cb);
                    acc[l][mf] = __builtin_amdgcn_mfma_f32_16x16x32_bf16(af, bf, acc[l][mf], 0, 0, 0);
                }
            }
            __syncthreads();
        }
    }

    const int scol = s0 * 64 + sq * 16 + lo;
    const float* bp = bias + (size_t)scol * 8;
    f32x4 bv0 = *reinterpret_cast<const f32x4*>(bp);
    f32x4 bv1 = *reinterpret_cast<const f32x4*>(bp + 4);
#pragma unroll
    for (int mf = 0; mf < 2; ++mf) {
#pragma unroll
        for (int r = 0; r < 4; ++r) {
            const int m = mhalf * 32 + mf * 16 + hi * 4 + r;
            f32x4 v0, v1;
#pragma unroll
            for (int l = 0; l < 4; ++l) {
                v0[l] = acc[l][mf][r]     + bv0[l];
                v1[l] = acc[l + 4][mf][r] + bv1[l];
            }
            float* op = out + (size_t)(b0 + m) * D2 + (size_t)scol * 8;
            *reinterpret_cast<f32x4*>(op)     = v0;
            *reinterpret_cast<f32x4*>(op + 4) = v1;
        }
    }
}

// ================= bottom fallback: round-1 fused kernel =================
__global__ __launch_bounds__(512, 1)
void butterfly_fused(const float* __restrict__ x,
                     const float* __restrict__ w1,
                     const float* __restrict__ w2,
                     const float* __restrict__ bias,
                     float* __restrict__ out)
{
    __shared__ bf16_t mid[64][520];
    __shared__ union {
        struct { bf16_t Xs[64][136]; bf16_t W1s[64][136]; } p1;
        bf16_t W2s[512][72];
    } u;
    __shared__ float bias_l[512];

    const int tid  = threadIdx.x;
    const int lane = tid & 63;
    const int wid  = tid >> 6;
    const int hi   = lane >> 4;
    const int lo   = lane & 15;

    const int bid  = blockIdx.x;
    const int l    = bid & 7;
    const int tile = bid >> 3;
    const int b0   = tile * 64;

    bias_l[tid] = bias[(tid << 3) + l];

    const int srow = tid >> 3;
    const int sseg = tid & 7;
    const int ttile = wid >> 1;
    const int mhalf = wid & 1;

    for (int kp = 0; kp < 8; ++kp) {
        f32x4 acc0 = {0.f, 0.f, 0.f, 0.f};
        f32x4 acc1 = {0.f, 0.f, 0.f, 0.f};
        for (int kc = 0; kc < 4; ++kc) {
            {
                const float* xp = x + (size_t)(b0 + srow) * D2 + kp * 512 + kc * 128 + sseg * 16;
                f32x4 a0 = *reinterpret_cast<const f32x4*>(xp);
                f32x4 a1 = *reinterpret_cast<const f32x4*>(xp + 4);
                f32x4 a2 = *reinterpret_cast<const f32x4*>(xp + 8);
                f32x4 a3 = *reinterpret_cast<const f32x4*>(xp + 12);
                cvt_store16(&u.p1.Xs[srow][sseg * 16],     a0, a1);
                cvt_store16(&u.p1.Xs[srow][sseg * 16 + 8], a2, a3);
            }
            {
                const float* wp = w1 + ((size_t)kp * 512 + (l + 8 * srow)) * 512 + kc * 128 + sseg * 16;
                f32x4 a0 = *reinterpret_cast<const f32x4*>(wp);
                f32x4 a1 = *reinterpret_cast<const f32x4*>(wp + 4);
                f32x4 a2 = *reinterpret_cast<const f32x4*>(wp + 8);
                f32x4 a3 = *reinterpret_cast<const f32x4*>(wp + 12);
                cvt_store16(&u.p1.W1s[srow][sseg * 16],     a0, a1);
                cvt_store16(&u.p1.W1s[srow][sseg * 16 + 8], a2, a3);
            }
            __syncthreads();
#pragma unroll
            for (int ks = 0; ks < 4; ++ks) {
                bf16x8 af  = *reinterpret_cast<const bf16x8*>(&u.p1.W1s[ttile * 16 + lo][ks * 32 + hi * 8]);
                bf16x8 bf0 = *reinterpret_cast<const bf16x8*>(&u.p1.Xs[mhalf * 32 + lo][ks * 32 + hi * 8]);
                bf16x8 bf1 = *reinterpret_cast<const bf16x8*>(&u.p1.Xs[mhalf * 32 + 16 + lo][ks * 32 + hi * 8]);
                acc0 = __builtin_amdgcn_mfma_f32_16x16x32_bf16(af, bf0, acc0, 0, 0, 0);
                acc1 = __builtin_amdgcn_mfma_f32_16x16x32_bf16(af, bf1, acc1, 0, 0, 0);
            }
            __syncthreads();
        }
        {
            const int rb = kp * 64 + ttile * 16 + hi * 4;
            bf16x4 p0, p1;
#pragma unroll
            for (int r = 0; r < 4; ++r) { p0[r] = (bf16_t)acc0[r]; p1[r] = (bf16_t)acc1[r]; }
            *reinterpret_cast<bf16x4*>(&mid[mhalf * 32 + lo][rb])      = p0;
            *reinterpret_cast<bf16x4*>(&mid[mhalf * 32 + 16 + lo][rb]) = p1;
        }
    }
    __syncthreads();

    const int mtile = wid >> 1;
    const int shalf = wid & 1;

    f32x4 acc[16];
#pragma unroll
    for (int j = 0; j < 16; ++j) acc[j] = {0.f, 0.f, 0.f, 0.f};

    for (int rc = 0; rc < 8; ++rc) {
#pragma unroll
        for (int ss = 0; ss < 8; ++ss) {
            const int s = (tid >> 3) + (ss << 6);
            const float* wp = w2 + ((size_t)l * 512 + s) * 512 + rc * 64 + sseg * 8;
            f32x4 a0 = *reinterpret_cast<const f32x4*>(wp);
            f32x4 a1 = *reinterpret_cast<const f32x4*>(wp + 4);
            cvt_store16(&u.W2s[s][sseg * 8], a0, a1);
        }
        __syncthreads();
#pragma unroll
        for (int ks = 0; ks < 2; ++ks) {
            bf16x8 af = *reinterpret_cast<const bf16x8*>(&mid[mtile * 16 + lo][rc * 64 + ks * 32 + hi * 8]);
#pragma unroll
            for (int j = 0; j < 16; ++j) {
                bf16x8 bfj = *reinterpret_cast<const bf16x8*>(&u.W2s[shalf * 256 + j * 16 + lo][ks * 32 + hi * 8]);
                acc[j] = __builtin_amdgcn_mfma_f32_16x16x32_bf16(af, bfj, acc[j], 0, 0, 0);
            }
        }
        __syncthreads();
    }

#pragma unroll
    for (int j = 0; j < 16; ++j) {
        const int s = shalf * 256 + j * 16 + lo;
        const float bv = bias_l[s];
        const size_t col = ((size_t)s << 3) + l;
#pragma unroll
        for (int r = 0; r < 4; ++r) {
            const int m = mtile * 16 + hi * 4 + r;
            out[(size_t)(b0 + m) * D2 + col] = acc[j][r] + bv;
        }
    }
}

extern "C" void kernel_launch(void* const* d_in, const int* in_sizes, int n_in,
                              void* d_out, int out_size, void* d_ws, size_t ws_size,
                              hipStream_t stream) {
    const float* x    = (const float*)d_in[0];
    const float* w1   = (const float*)d_in[1];
    const float* w2   = (const float*)d_in[2];
    const float* bias = (const float*)d_in[3];
    float* out = (float*)d_out;

    if (ws_size >= WS_NEED) {
        bf16_t* mid = (bf16_t*)d_ws;
        bf16x8* w1p = (bf16x8*)((char*)d_ws + W1P_OFF);
        bf16x8* w2p = (bf16x8*)((char*)d_ws + W2P_OFF);
        hipLaunchKernelGGL(prep_w1, dim3(1024), dim3(256), 0, stream, w1, w1p);
        hipLaunchKernelGGL(prep_w2, dim3(1024), dim3(256), 0, stream, w2, w2p);
        hipLaunchKernelGGL(butterfly_k1b, dim3(1024), dim3(512), 0, stream, x, w1p, mid);
        hipLaunchKernelGGL(butterfly_k2b, dim3(1024), dim3(512), 0, stream,
                           mid, (const char*)w2p, bias, out);
    } else if (ws_size >= MID_BYTES) {
        bf16_t* mid = (bf16_t*)d_ws;
        hipLaunchKernelGGL(butterfly_k1, dim3(1024), dim3(512), 0, stream, x, w1, mid);
        hipLaunchKernelGGL(butterfly_k2, dim3(1024), dim3(512), 0, stream, mid, w2, bias, out);
    } else {
        hipLaunchKernelGGL(butterfly_fused, dim3(1024), dim3(512), 0, stream, x, w1, w2, bias, out);
    }
}